// Round 15
// baseline (107.394 us; speedup 1.0000x reference)
//
#include <hip/hip_runtime.h>
#include <math.h>

#define B_   2
#define S_   2048
#define DIM_ 1024
#define H_   16
#define HD_  64
#define BS_  (B_ * S_)              // 4096
#define BHSD ((size_t)B_ * H_ * S_ * HD_)   // 4M elements
#define CEXP 0.1803368801111244f    // log2(e) / sqrt(64)

typedef unsigned short u16;
typedef unsigned int   u32;
typedef short s16x8 __attribute__((ext_vector_type(8)));
typedef float f32x4 __attribute__((ext_vector_type(4)));

#define MFMA16(a, b, c) __builtin_amdgcn_mfma_f32_16x16x32_bf16((a), (b), (c), 0, 0, 0)

__device__ __forceinline__ u16 f2bf(float f) {
    u32 u = __float_as_uint(f);
    u += 0x7fffu + ((u >> 16) & 1u);            // RNE
    return (u16)(u >> 16);
}
__device__ __forceinline__ float bf2f(u16 h) {
    return __uint_as_float(((u32)h) << 16);
}
__device__ __forceinline__ u32 cvt_pk_bf16(float a, float b) {
    u32 r;
    asm("v_cvt_pk_bf16_f32 %0, %1, %2" : "=v"(r) : "v"(a), "v"(b));
    return r;
}
// async global->LDS, 16B/lane; LDS dest must be WAVE-UNIFORM base (+lane*16)
__device__ __forceinline__ void gl16(void* lds, const void* g) {
    __builtin_amdgcn_global_load_lds(
        (__attribute__((address_space(1))) void*)(g),
        (__attribute__((address_space(3))) void*)(lds), 16, 0, 0);
}

// ---------------------------------------------------------------------------
// prep: fused cvt_x | weight transpose (+q/k col-permutation) | cos/sin table
// | bias concat (permuted). Dispatch by blockIdx.x range.
// ---------------------------------------------------------------------------
__global__ __launch_bounds__(256) void prep(
    const float* __restrict__ x, u16* __restrict__ xb,
    const float* __restrict__ W0, const float* __restrict__ W1,
    const float* __restrict__ W2, const float* __restrict__ W3,
    u16* __restrict__ T0, u16* __restrict__ T1,
    u16* __restrict__ T2, u16* __restrict__ T3,
    const float* __restrict__ bq, const float* __restrict__ bk,
    const float* __restrict__ bv, float* __restrict__ bias3,
    const float* __restrict__ theta, float2* __restrict__ cs)
{
    __shared__ float tile[32][33];
    const int bid = blockIdx.x, tid = threadIdx.x;

    if (bid < 2048) {                       // ---- x -> bf16
        const int i = bid * 256 + tid;
        const float4 a = *(const float4*)(x + (size_t)i * 8);
        const float4 b = *(const float4*)(x + (size_t)i * 8 + 4);
        s16x8 o;
        o[0] = (short)f2bf(a.x); o[1] = (short)f2bf(a.y);
        o[2] = (short)f2bf(a.z); o[3] = (short)f2bf(a.w);
        o[4] = (short)f2bf(b.x); o[5] = (short)f2bf(b.y);
        o[6] = (short)f2bf(b.z); o[7] = (short)f2bf(b.w);
        *(s16x8*)(xb + (size_t)i * 8) = o;
    } else if (bid < 6144) {                // ---- W transpose
        const int idx = bid - 2048;
        const int z = idx >> 10;
        const float* W; u16* T;
        switch (z) {
            case 0: W = W0; T = T0; break;
            case 1: W = W1; T = T1; break;
            case 2: W = W2; T = T2; break;
            default: W = W3; T = T3; break;
        }
        const int n0 = ((idx >> 5) & 31) * 32, k0 = (idx & 31) * 32;
        const int c = tid & 31, rr = tid >> 5;
#pragma unroll
        for (int i = 0; i < 4; ++i) {
            const int k = rr + i * 8;
            tile[k][c] = W[(size_t)(k0 + k) * DIM_ + n0 + c];
        }
        __syncthreads();
#pragma unroll
        for (int i = 0; i < 4; ++i) {
            const int col = n0 + rr + i * 8;
            int pcol = col;
            if (z < 2) {                    // rope col-perm: even->lo, odd->hi
                const int dd = col & 63;
                const int pd = (dd & 1) ? 32 + (dd >> 1) : (dd >> 1);
                pcol = (col & ~63) | pd;
            }
            T[(size_t)pcol * DIM_ + k0 + c] = f2bf(tile[c][rr + i * 8]);
        }
    } else if (bid < 6400) {                // ---- cos/sin table
        const int idx = bid - 6144;
        const int s = idx * 8 + (tid >> 5), j = tid & 31;
        float sn, cn;
        sincosf((float)s * theta[j], &sn, &cn);
        cs[(s << 5) + j] = make_float2(cn, sn);
    } else {                                // ---- bias concat (permuted q,k)
        const int i = (bid - 6400) * 256 + tid;   // 0..3071
        const int which = i >> 10, local = i & 1023;
        const float v = (which == 0) ? bq[local]
                      : (which == 1) ? bk[local] : bv[local];
        int dst = i;
        if (which < 2) {
            const int dd = local & 63;
            const int pd = (dd & 1) ? 32 + (dd >> 1) : (dd >> 1);
            dst = which * 1024 + (local & ~63) + pd;
        }
        bias3[dst] = v;
    }
}

// ---------------------------------------------------------------------------
// bf16 MFMA GEMM (QKV), tile 128 x 128, BK=64, 256 threads (4 waves, 2x2).
// A,Bt staged via global_load_lds (16B) into linear LDS, XOR-swizzled via
// pre-swizzled global source. Epilogue: bf16 head-major out into q|k|VT.
//   q,k: fused RoPE (weights col-permuted; pairs (n, n+2) in-register) +
//        q pre-scaled by log2(e)/8.
//   VT : V transposed with kv-bit perm pi: bits[5,4,3,2]->[2,5,4,3]
//        (makes the attention PV A-fragment lane-local).
// ---------------------------------------------------------------------------
__global__ __launch_bounds__(256, 3) void gemm_qkv(
    const u16* __restrict__ A, const u16* __restrict__ Bt,
    const float* __restrict__ bias, u16* __restrict__ Y,
    const float2* __restrict__ cs)
{
    __shared__ u16 As[128 * 64];
    __shared__ u16 Bs[128 * 64];

    const int tid = threadIdx.x, lane = tid & 63, wid = tid >> 6;
    const int l15 = lane & 15, lg = lane >> 4;
    const int row0 = blockIdx.x * 128, col0 = blockIdx.y * 128;
    const int wr = (wid >> 1) * 64;
    const int wc = (wid & 1) * 64;
    constexpr int NM = 4, NN = 4, BCH = 4;

    const int l8 = lane >> 3, l7 = lane & 7;
    const int colE = ((l7 ^ l8) << 3);          // k-element offset (swizzled)

    const u16* aptr[4]; u16* aldp[4];
#pragma unroll
    for (int i = 0; i < 4; ++i) {
        const int ci = wid * 4 + i;
        aptr[i] = A + (size_t)(row0 + ci * 8 + l8) * DIM_ + colE;
        aldp[i] = As + ci * 512;
    }
    const u16* bptr[BCH]; u16* bldp[BCH];
#pragma unroll
    for (int i = 0; i < BCH; ++i) {
        const int ci = wid * BCH + i;
        bptr[i] = Bt + (size_t)(col0 + ci * 8 + l8) * DIM_ + colE;
        bldp[i] = Bs + ci * 512;
    }

    f32x4 acc[NM][NN];
#pragma unroll
    for (int m = 0; m < NM; ++m)
#pragma unroll
        for (int n = 0; n < NN; ++n) acc[m][n] = (f32x4){0.f, 0.f, 0.f, 0.f};

    for (int k0 = 0; k0 < DIM_; k0 += 64) {
        __syncthreads();   // previous frag reads done
#pragma unroll
        for (int i = 0; i < 4; ++i) gl16(aldp[i], aptr[i]);
#pragma unroll
        for (int i = 0; i < BCH; ++i) gl16(bldp[i], bptr[i]);
#pragma unroll
        for (int i = 0; i < 4; ++i) aptr[i] += 64;
#pragma unroll
        for (int i = 0; i < BCH; ++i) bptr[i] += 64;
        __syncthreads();   // loads drained

        s16x8 af[NM][2], bfr[NN][2];
#pragma unroll
        for (int m = 0; m < NM; ++m) {
            const int row = wr + m * 16 + l15;
#pragma unroll
            for (int kf = 0; kf < 2; ++kf)
                af[m][kf] = *(const s16x8*)&As[row * 64 +
                    (((kf * 64 + lg * 16) ^ ((l15 & 7) << 4)) >> 1)];
        }
#pragma unroll
        for (int n = 0; n < NN; ++n) {
            const int row = wc + n * 16 + l15;
#pragma unroll
            for (int kf = 0; kf < 2; ++kf)
                bfr[n][kf] = *(const s16x8*)&Bs[row * 64 +
                    (((kf * 64 + lg * 16) ^ ((l15 & 7) << 4)) >> 1)];
        }
        __builtin_amdgcn_s_setprio(1);
#pragma unroll
        for (int m = 0; m < NM; ++m)
#pragma unroll
            for (int n = 0; n < NN; ++n) {
                acc[m][n] = MFMA16(af[m][0], bfr[n][0], acc[m][n]);
                acc[m][n] = MFMA16(af[m][1], bfr[n][1], acc[m][n]);
            }
        __builtin_amdgcn_s_setprio(0);
    }

    // ---- epilogue (q|k rope'd, VT pi-permuted)
    const int whichq = (col0 + wc) >> 10;          // wave-uniform
    if (whichq < 2) {
        const float sclw = (whichq == 0) ? CEXP : 1.0f;
#pragma unroll
        for (int n = 0; n < 2; ++n) {
            const int cc0 = col0 + wc + n * 16 + l15;
            const int j = n * 16 + l15;            // 0..31
            const float bv0 = bias[cc0];
            const float bv1 = bias[cc0 + 32];
            const int hh = (cc0 >> 6) & (H_ - 1);
#pragma unroll
            for (int m = 0; m < NM; ++m)
#pragma unroll
                for (int r = 0; r < 4; ++r) {
                    const int rr = row0 + wr + m * 16 + lg * 4 + r;
                    const int b = rr >> 11, s = rr & (S_ - 1);
                    const float2 csv = cs[(s << 5) + j];
                    const float v0 = acc[m][n][r] + bv0;
                    const float v1 = acc[m][n + 2][r] + bv1;
                    const size_t base = (size_t)whichq * BHSD
                        + (((size_t)b * H_ + hh) * S_ + s) * HD_;
                    Y[base + j]      = f2bf((v0 * csv.x - v1 * csv.y) * sclw);
                    Y[base + j + 32] = f2bf((v0 * csv.y + v1 * csv.x) * sclw);
                }
        }
    } else {
#pragma unroll
        for (int n = 0; n < NN; ++n) {
            const int cc = col0 + wc + n * 16 + l15;
            const float bv = bias[cc];
            const int hh = (cc >> 6) & (H_ - 1), d = cc & 63;
#pragma unroll
            for (int m = 0; m < NM; ++m)
#pragma unroll
                for (int r = 0; r < 4; ++r) {
                    const int rr = row0 + wr + m * 16 + lg * 4 + r;
                    const int b = rr >> 11, s = rr & (S_ - 1);
                    // V^T with kv perm pi: bits {2,3}->{3,4}, {4}->{5}, {5}->{2}
                    const int sp = (s & ~60) | ((s & 12) << 1)
                                 | ((s & 16) << 1) | ((s & 32) >> 3);
                    Y[2 * BHSD + ((size_t)(b * H_ + hh) * HD_ + d) * S_ + sp] =
                        f2bf(acc[m][n][r] + bv);
                }
        }
    }
}

// ---------------------------------------------------------------------------
// Causal flash attention, max-free + SPLIT-KV-2 (partials only; merge is
// fused into the O-projection GEMM). Each (bh, qt) 64-row q-tile is computed
// by TWO blocks (kv halves); max-free softmax makes partials purely additive.
// Grid (32 bh FAST, 64 items) = 2048 blocks; 5 co-resident blocks/CU.
// Band-balanced item map; heavy halves dispatch first.
// Partials: O bf16 [item][64][64], l f32 [item][64]. No fences, no atomics.
// ---------------------------------------------------------------------------
__global__ __launch_bounds__(256, 5) void attn_q(
    const u16* __restrict__ Q, const u16* __restrict__ K,
    const u16* __restrict__ VT, u16* __restrict__ Opart,
    float* __restrict__ lpart)
{
    const int bh = blockIdx.x;
    const int y  = blockIdx.y;                // 0..63
    const int a = y >> 4, r0_ = y & 15;
    const int b = r0_ >> 1, half = r0_ & 1;
    const int qt = (a == 0) ? (31 - b) : (a == 1) ? (16 + b)
                 : (a == 2) ? (15 - b) : b;    // band-balanced map
    const int T = qt + 1, h0 = (T + 1) >> 1;
    const int kvlo = half ? h0 : 0;
    const int kvhi = half ? T : h0;
    const int nst = kvhi - kvlo;               // 0 possible (qt=0, half=1)

    const u16* Qg = Q + (size_t)bh * S_ * HD_;
    const u16* Kg = K + (size_t)bh * S_ * HD_;
    const u16* Vg = VT + (size_t)bh * HD_ * S_;   // pi-permuted [64][2048]

    __shared__ u16 Ks[2][64 * 64];   // 2 x 8 KB
    __shared__ u16 Vs[2][64 * 64];   // 2 x 8 KB

    const int tid = threadIdx.x;
    const int w = tid >> 6, lane = tid & 63;
    const int q0 = qt * 64 + w * 16;
    const int l15 = lane & 15, lg = lane >> 4;

    // staging: per wave 2 K-chunks + 2 V-chunks (8 rows x 64 cols each)
    const int crow = lane >> 3, cslt = lane & 7;

    auto stage = [&](int bufi, int j0) {
#pragma unroll
        for (int i = 0; i < 2; ++i) {
            const int c = w * 2 + i;                  // chunk 0..7
            const int row = c * 8 + crow;             // 0..63
            const int soff = ((cslt ^ (row & 7)) << 3);
            gl16(&Ks[bufi][c * 512], Kg + (size_t)(j0 + row) * HD_ + soff);
            gl16(&Vs[bufi][c * 512], Vg + (size_t)row * S_ + j0 + soff);
        }
    };

    // Q fragments: rows q0 + l15 (rope'd, q pre-scaled by log2(e)/8)
    s16x8 qf[2];
    {
        const u16* qrow = Qg + (size_t)(q0 + l15) * HD_ + lg * 8;
        qf[0] = *(const s16x8*)(qrow);
        qf[1] = *(const s16x8*)(qrow + 32);
    }

    // ones B-fragment (bf16 1.0) for MFMA row-sums
    s16x8 onesv;
#pragma unroll
    for (int i = 0; i < 8; ++i) onesv[i] = (short)0x3F80;

    f32x4 o[4], ol;
#pragma unroll
    for (int n = 0; n < 4; ++n) o[n] = (f32x4){0.f, 0.f, 0.f, 0.f};
    ol = (f32x4){0.f, 0.f, 0.f, 0.f};

    stage(0, kvlo * 64);
    __syncthreads();

    int buf = 0;
    for (int s = 0; s < nst; ++s) {
        const int t = kvlo + s;
        if (s + 1 < nst) stage(buf ^ 1, (t + 1) * 64);   // prefetch

        const u16* Kb = Ks[buf];
        const u16* Vb = Vs[buf];

        // ---- swapped QK^T: sc[sub][r] = S[kv=t*64+sub*16+lg*4+r][q0+l15]
        f32x4 sc[4];
        __builtin_amdgcn_s_setprio(1);
#pragma unroll
        for (int sub = 0; sub < 4; ++sub) {
            const int kr = sub * 16 + l15;
            const s16x8 kf0 = *(const s16x8*)&Kb[kr * 64 + ((lg ^ (kr & 7)) << 3)];
            const s16x8 kf1 = *(const s16x8*)&Kb[kr * 64 + (((lg + 4) ^ (kr & 7)) << 3)];
            f32x4 z = (f32x4){0.f, 0.f, 0.f, 0.f};
            z = MFMA16(kf0, qf[0], z);
            sc[sub] = MFMA16(kf1, qf[1], z);
        }
        __builtin_amdgcn_s_setprio(0);

        if (t == qt) {      // diagonal 64-tile: aligned 16x16 subs
#pragma unroll
            for (int sub = 0; sub < 4; ++sub) {
                if (sub == w) {
#pragma unroll
                    for (int r = 0; r < 4; ++r)
                        if (lg * 4 + r > l15) sc[sub][r] = -1e30f;
                } else if (sub > w) {
#pragma unroll
                    for (int r = 0; r < 4; ++r) sc[sub][r] = -1e30f;
                }
            }
        }

        // ---- max-free softmax: p = exp2(s); masked -1e30 -> exp2 -> 0
        float p[4][4];
#pragma unroll
        for (int sub = 0; sub < 4; ++sub)
#pragma unroll
            for (int r = 0; r < 4; ++r)
                p[sub][r] = __builtin_amdgcn_exp2f(sc[sub][r]);

        // ---- PV + row-sum: lane-local A-fragments (pi-permuted V^T)
        union { s16x8 v; u32 w4[4]; } af[2];
#pragma unroll
        for (int step = 0; step < 2; ++step)
#pragma unroll
            for (int jj = 0; jj < 4; ++jj) {
                const int sub = (jj >> 1) * 2 + step;
                const int rr0 = (jj & 1) * 2;
                af[step].w4[jj] = cvt_pk_bf16(p[sub][rr0], p[sub][rr0 + 1]);
            }
        __builtin_amdgcn_s_setprio(1);
#pragma unroll
        for (int n = 0; n < 4; ++n) {
            const int d = n * 16 + l15;
            const s16x8 vf0 = *(const s16x8*)&Vb[d * 64 + ((lg ^ (d & 7)) << 3)];
            const s16x8 vf1 = *(const s16x8*)&Vb[d * 64 + (((lg + 4) ^ (d & 7)) << 3)];
            o[n] = MFMA16(af[0].v, vf0, o[n]);
            o[n] = MFMA16(af[1].v, vf1, o[n]);
        }
        ol = MFMA16(af[0].v, onesv, ol);    // l[q] = sum_kv p (matrix pipe)
        ol = MFMA16(af[1].v, onesv, ol);
        __builtin_amdgcn_s_setprio(0);

        __syncthreads();   // drains prefetch; buffer handoff
        buf ^= 1;
    }

    // ---- epilogue: write additive partials (O bf16, l f32)
    const size_t it = ((size_t)(bh * 32 + qt) * 2 + half);
    u16* op = Opart + it * 4096;
#pragma unroll
    for (int r = 0; r < 4; ++r) {
        const int rowl = w * 16 + lg * 4 + r;
#pragma unroll
        for (int n = 0; n < 4; ++n)
            op[rowl * 64 + n * 16 + l15] = f2bf(o[n][r]);
        if (l15 == 0) lpart[it * 64 + rowl] = ol[r];
    }
}

// ---------------------------------------------------------------------------
// O-projection GEMM with FUSED split-kv merge in the A-staging path.
// A[rr][k] = (bf16(O0) + bf16(O1)) / (l0 + l1) for row rr = b*2048+s,
// head h = k0>>6, d = k&63 -- loaded from partials, merged in registers,
// ds_written to the SAME linear LDS slot global_load_lds would fill
// (global source keeps the colE pre-swizzle -> fragment reads unchanged).
// Tile 128x64, BK=64, 256 threads; fp32 row-major out + bias.
// ---------------------------------------------------------------------------
__global__ __launch_bounds__(256, 3) void gemm_oproj(
    const u16* __restrict__ Opart, const float* __restrict__ lpart,
    const u16* __restrict__ Bt, const float* __restrict__ bias,
    float* __restrict__ Y)
{
    __shared__ u16 As[128 * 64];   // 16 KB
    __shared__ u16 Bs[64 * 64];    //  8 KB

    const int tid = threadIdx.x, lane = tid & 63, wid = tid >> 6;
    const int l15 = lane & 15, lg = lane >> 4;
    const int row0 = blockIdx.x * 128, col0 = blockIdx.y * 64;
    const int wr = (wid >> 1) * 64;
    const int wc = (wid & 1) * 32;

    const int l8 = lane >> 3, l7 = lane & 7;
    const int colE = ((l7 ^ l8) << 3);          // d-offset (swizzled)

    // per-chunk A coords: it0 = base + h*64 (h = k0>>6 varies per step)
    int base_[4], rowl_[4];
#pragma unroll
    for (int i = 0; i < 4; ++i) {
        const int ci = wid * 4 + i;
        const int rr = row0 + ci * 8 + l8;
        const int b = rr >> 11, s = rr & (S_ - 1);
        base_[i] = b * 1024 + (s >> 6) * 2;     // (b*16*32 + qt)*2 sans h
        rowl_[i] = s & 63;
    }
    const u16* bptr[2]; u16* bldp[2];
#pragma unroll
    for (int i = 0; i < 2; ++i) {
        const int ci = wid * 2 + i;
        bptr[i] = Bt + (size_t)(col0 + ci * 8 + l8) * DIM_ + colE;
        bldp[i] = Bs + ci * 512;
    }

    f32x4 acc[4][2];
#pragma unroll
    for (int m = 0; m < 4; ++m)
#pragma unroll
        for (int n = 0; n < 2; ++n) acc[m][n] = (f32x4){0.f, 0.f, 0.f, 0.f};

    for (int k0 = 0; k0 < DIM_; k0 += 64) {
        const int h = k0 >> 6;
        __syncthreads();   // previous frag reads done
#pragma unroll
        for (int i = 0; i < 2; ++i) gl16(bldp[i], bptr[i]);
#pragma unroll
        for (int i = 0; i < 2; ++i) bptr[i] += 64;

        // A: load both partials + l, merge, ds_write (linear slot = gl16's)
#pragma unroll
        for (int i = 0; i < 4; ++i) {
            const int it0 = base_[i] + h * 64;
            const u16* p0 = Opart + (size_t)it0 * 4096 + rowl_[i] * 64 + colE;
            const s16x8 a0 = *(const s16x8*)p0;
            const s16x8 a1 = *(const s16x8*)(p0 + 4096);
            const float lsum = lpart[it0 * 64 + rowl_[i]]
                             + lpart[it0 * 64 + 64 + rowl_[i]];
            const float inv = __builtin_amdgcn_rcpf(lsum);
            union { s16x8 v; u32 w4[4]; } am;
#pragma unroll
            for (int j = 0; j < 4; ++j) {
                const float v0 = (bf2f((u16)a0[2 * j])     + bf2f((u16)a1[2 * j]))     * inv;
                const float v1 = (bf2f((u16)a0[2 * j + 1]) + bf2f((u16)a1[2 * j + 1])) * inv;
                am.w4[j] = cvt_pk_bf16(v0, v1);
            }
            const int ci = wid * 4 + i;
            *(s16x8*)&As[ci * 512 + lane * 8] = am.v;
        }
        __syncthreads();   // A written + B gl16 drained

        s16x8 af[4][2], bfr[2][2];
#pragma unroll
        for (int m = 0; m < 4; ++m) {
            const int row = wr + m * 16 + l15;
#pragma unroll
            for (int kf = 0; kf < 2; ++kf)
                af[m][kf] = *(const s16x8*)&As[row * 64 +
                    (((kf * 64 + lg * 16) ^ ((l15 & 7) << 4)) >> 1)];
        }
#pragma unroll
        for (int n = 0; n < 2; ++n) {
            const int row = wc + n * 16 + l15;
#pragma unroll
            for (int kf = 0; kf < 2; ++kf)
                bfr[n][kf] = *(const s16x8*)&Bs[row * 64 +
                    (((kf * 64 + lg * 16) ^ ((l15 & 7) << 4)) >> 1)];
        }
        __builtin_amdgcn_s_setprio(1);
#pragma unroll
        for (int m = 0; m < 4; ++m)
#pragma unroll
            for (int n = 0; n < 2; ++n) {
                acc[m][n] = MFMA16(af[m][0], bfr[n][0], acc[m][n]);
                acc[m][n] = MFMA16(af[m][1], bfr[n][1], acc[m][n]);
            }
        __builtin_amdgcn_s_setprio(0);
    }

    // ---- epilogue: fp32 row-major + bias
#pragma unroll
    for (int n = 0; n < 2; ++n) {
        const int cc = col0 + wc + n * 16 + l15;
        const float bv = bias[cc];
#pragma unroll
        for (int m = 0; m < 4; ++m)
#pragma unroll
            for (int r = 0; r < 4; ++r) {
                const int rr = row0 + wr + m * 16 + lg * 4 + r;
                Y[(size_t)rr * DIM_ + cc] = acc[m][n][r] + bv;
            }
    }
}

// ---------------------------------------------------------------------------
extern "C" void kernel_launch(void* const* d_in, const int* in_sizes, int n_in,
                              void* d_out, int out_size, void* d_ws, size_t ws_size,
                              hipStream_t stream)
{
    (void)in_sizes; (void)n_in; (void)out_size; (void)ws_size;
    const float* x     = (const float*)d_in[0];
    const float* theta = (const float*)d_in[2];
    const float* Wq    = (const float*)d_in[3];
    const float* bq    = (const float*)d_in[4];
    const float* Wk    = (const float*)d_in[5];
    const float* bk    = (const float*)d_in[6];
    const float* Wv    = (const float*)d_in[7];
    const float* bv    = (const float*)d_in[8];
    const float* Wo    = (const float*)d_in[9];
    const float* bo    = (const float*)d_in[10];
    float* out = (float*)d_out;

    // ws (u16): xb 4M | wtq|wtk|wtv 3M | wto 1M | q 4M | k 4M | VT 4M |
    //           bias3 (4096 f32) | cs (2048x32 float2) | Opart 8M u16 | lpart
    u16* xb  = (u16*)d_ws;
    u16* wtq = xb + (size_t)BS_ * DIM_;
    u16* wtk = wtq + (size_t)DIM_ * DIM_;
    u16* wtv = wtk + (size_t)DIM_ * DIM_;
    u16* wto = wtv + (size_t)DIM_ * DIM_;
    u16* qws = wto + (size_t)DIM_ * DIM_;
    u16* kws = qws + BHSD;
    u16* vtw = kws + BHSD;
    float* bias3 = (float*)(vtw + BHSD);
    float2* cs = (float2*)(bias3 + 4096);
    u16* opart = (u16*)(cs + (size_t)S_ * 32);
    float* lpart = (float*)(opart + (size_t)2048 * 4096);

    // fused prep: cvt_x | wtrans(+perm) | cos/sin table | bias concat(+perm)
    prep<<<dim3(6412), dim3(256), 0, stream>>>(
        x, xb, Wq, Wk, Wv, Wo, wtq, wtk, wtv, wto, bq, bk, bv, bias3, theta, cs);

    // fused QKV projection: q,k rope'd head-major; V transposed+pi-permuted
    gemm_qkv<<<dim3(32, 24), dim3(256), 0, stream>>>(xb, wtq, bias3, qws, cs);

    // split-kv max-free attention: partials only (merge fused into O-proj)
    attn_q<<<dim3(32, 64), dim3(256), 0, stream>>>(qws, kws, vtw, opart, lpart);

    // output projection with fused split-kv merge in A-staging
    gemm_oproj<<<dim3(32, 16), dim3(256), 0, stream>>>(
        opart, lpart, wto, bo, out);
}

// Round 16
// 96.165 us; speedup vs baseline: 1.1168x; 1.1168x over previous
//
#include <hip/hip_runtime.h>
#include <math.h>

#define B_   2
#define S_   2048
#define DIM_ 1024
#define H_   16
#define HD_  64
#define BS_  (B_ * S_)              // 4096
#define BHSD ((size_t)B_ * H_ * S_ * HD_)   // 4M elements
#define CEXP 0.1803368801111244f    // log2(e) / sqrt(64)

typedef unsigned short u16;
typedef unsigned int   u32;
typedef short s16x8 __attribute__((ext_vector_type(8)));
typedef float f32x4 __attribute__((ext_vector_type(4)));

#define MFMA16(a, b, c) __builtin_amdgcn_mfma_f32_16x16x32_bf16((a), (b), (c), 0, 0, 0)

__device__ __forceinline__ u16 f2bf(float f) {
    u32 u = __float_as_uint(f);
    u += 0x7fffu + ((u >> 16) & 1u);            // RNE
    return (u16)(u >> 16);
}
__device__ __forceinline__ u32 cvt_pk_bf16(float a, float b) {
    u32 r;
    asm("v_cvt_pk_bf16_f32 %0, %1, %2" : "=v"(r) : "v"(a), "v"(b));
    return r;
}
// async global->LDS, 16B/lane; LDS dest must be WAVE-UNIFORM base (+lane*16)
__device__ __forceinline__ void gl16(void* lds, const void* g) {
    __builtin_amdgcn_global_load_lds(
        (__attribute__((address_space(1))) void*)(g),
        (__attribute__((address_space(3))) void*)(lds), 16, 0, 0);
}

// ---------------------------------------------------------------------------
// prep: fused cvt_x | weight transpose (+q/k col-permutation) | cos/sin table
// | bias concat (permuted). Dispatch by blockIdx.x range.
// ---------------------------------------------------------------------------
__global__ __launch_bounds__(256) void prep(
    const float* __restrict__ x, u16* __restrict__ xb,
    const float* __restrict__ W0, const float* __restrict__ W1,
    const float* __restrict__ W2, const float* __restrict__ W3,
    u16* __restrict__ T0, u16* __restrict__ T1,
    u16* __restrict__ T2, u16* __restrict__ T3,
    const float* __restrict__ bq, const float* __restrict__ bk,
    const float* __restrict__ bv, float* __restrict__ bias3,
    const float* __restrict__ theta, float2* __restrict__ cs)
{
    __shared__ float tile[32][33];
    const int bid = blockIdx.x, tid = threadIdx.x;

    if (bid < 2048) {                       // ---- x -> bf16
        const int i = bid * 256 + tid;
        const float4 a = *(const float4*)(x + (size_t)i * 8);
        const float4 b = *(const float4*)(x + (size_t)i * 8 + 4);
        s16x8 o;
        o[0] = (short)f2bf(a.x); o[1] = (short)f2bf(a.y);
        o[2] = (short)f2bf(a.z); o[3] = (short)f2bf(a.w);
        o[4] = (short)f2bf(b.x); o[5] = (short)f2bf(b.y);
        o[6] = (short)f2bf(b.z); o[7] = (short)f2bf(b.w);
        *(s16x8*)(xb + (size_t)i * 8) = o;
    } else if (bid < 6144) {                // ---- W transpose
        const int idx = bid - 2048;
        const int z = idx >> 10;
        const float* W; u16* T;
        switch (z) {
            case 0: W = W0; T = T0; break;
            case 1: W = W1; T = T1; break;
            case 2: W = W2; T = T2; break;
            default: W = W3; T = T3; break;
        }
        const int n0 = ((idx >> 5) & 31) * 32, k0 = (idx & 31) * 32;
        const int c = tid & 31, rr = tid >> 5;
#pragma unroll
        for (int i = 0; i < 4; ++i) {
            const int k = rr + i * 8;
            tile[k][c] = W[(size_t)(k0 + k) * DIM_ + n0 + c];
        }
        __syncthreads();
#pragma unroll
        for (int i = 0; i < 4; ++i) {
            const int col = n0 + rr + i * 8;
            int pcol = col;
            if (z < 2) {                    // rope col-perm: even->lo, odd->hi
                const int dd = col & 63;
                const int pd = (dd & 1) ? 32 + (dd >> 1) : (dd >> 1);
                pcol = (col & ~63) | pd;
            }
            T[(size_t)pcol * DIM_ + k0 + c] = f2bf(tile[c][rr + i * 8]);
        }
    } else if (bid < 6400) {                // ---- cos/sin table
        const int idx = bid - 6144;
        const int s = idx * 8 + (tid >> 5), j = tid & 31;
        float sn, cn;
        sincosf((float)s * theta[j], &sn, &cn);
        cs[(s << 5) + j] = make_float2(cn, sn);
    } else {                                // ---- bias concat (permuted q,k)
        const int i = (bid - 6400) * 256 + tid;   // 0..3071
        const int which = i >> 10, local = i & 1023;
        const float v = (which == 0) ? bq[local]
                      : (which == 1) ? bk[local] : bv[local];
        int dst = i;
        if (which < 2) {
            const int dd = local & 63;
            const int pd = (dd & 1) ? 32 + (dd >> 1) : (dd >> 1);
            dst = which * 1024 + (local & ~63) + pd;
        }
        bias3[dst] = v;
    }
}

// ---------------------------------------------------------------------------
// bf16 MFMA GEMM, tile 128 x BN, BK=64, 256 threads (4 waves, 2x2 quadrants).
// A,Bt staged via global_load_lds (16B) into linear LDS, XOR-swizzled via
// pre-swizzled global source.
// EPI 0: bf16 head-major out into q|k|VT.
//   q,k: fused RoPE (weights col-permuted; pairs (n, n+2) in-register) +
//        q pre-scaled by log2(e)/8.
//   VT : V transposed with kv-bit perm pi: bits[5,4,3,2]->[2,5,4,3]
//        (makes the attention PV A-fragment lane-local).
// EPI 1: fp32 row-major out.
// ---------------------------------------------------------------------------
template<int BN, int HMIN, int EPI>
__global__ __launch_bounds__(256, 3) void gemm_mfma(
    const u16* __restrict__ A, const u16* __restrict__ Bt,
    const float* __restrict__ bias, void* __restrict__ Yv,
    const float2* __restrict__ cs)
{
    __shared__ u16 As[128 * 64];
    __shared__ u16 Bs[BN * 64];

    const int tid = threadIdx.x, lane = tid & 63, wid = tid >> 6;
    const int l15 = lane & 15, lg = lane >> 4;
    const int row0 = blockIdx.x * 128, col0 = blockIdx.y * BN;
    const int wr = (wid >> 1) * 64;
    const int wc = (wid & 1) * (BN / 2);
    constexpr int NM = 4, NN = BN / 32, BCH = BN / 32;

    const int l8 = lane >> 3, l7 = lane & 7;
    const int colE = ((l7 ^ l8) << 3);          // k-element offset (swizzled)

    const u16* aptr[4]; u16* aldp[4];
#pragma unroll
    for (int i = 0; i < 4; ++i) {
        const int ci = wid * 4 + i;
        const int rr = row0 + ci * 8 + l8;
        size_t a0;
        if (HMIN)
            a0 = (((size_t)(rr >> 11) * H_) * S_ + (rr & (S_ - 1))) * HD_ + colE;
        else
            a0 = (size_t)rr * DIM_ + colE;
        aptr[i] = A + a0;
        aldp[i] = As + ci * 512;
    }
    const u16* bptr[BCH]; u16* bldp[BCH];
#pragma unroll
    for (int i = 0; i < BCH; ++i) {
        const int ci = wid * BCH + i;
        const int rr = col0 + ci * 8 + l8;
        bptr[i] = Bt + (size_t)rr * DIM_ + colE;
        bldp[i] = Bs + ci * 512;
    }
    const size_t astep = HMIN ? (size_t)S_ * HD_ : 64;

    f32x4 acc[NM][NN];
#pragma unroll
    for (int m = 0; m < NM; ++m)
#pragma unroll
        for (int n = 0; n < NN; ++n) acc[m][n] = (f32x4){0.f, 0.f, 0.f, 0.f};

    for (int k0 = 0; k0 < DIM_; k0 += 64) {
        __syncthreads();   // previous frag reads done
#pragma unroll
        for (int i = 0; i < 4; ++i) gl16(aldp[i], aptr[i]);
#pragma unroll
        for (int i = 0; i < BCH; ++i) gl16(bldp[i], bptr[i]);
#pragma unroll
        for (int i = 0; i < 4; ++i) aptr[i] += astep;
#pragma unroll
        for (int i = 0; i < BCH; ++i) bptr[i] += 64;
        __syncthreads();   // loads drained

        s16x8 af[NM][2], bfr[NN][2];
#pragma unroll
        for (int m = 0; m < NM; ++m) {
            const int row = wr + m * 16 + l15;
#pragma unroll
            for (int kf = 0; kf < 2; ++kf)
                af[m][kf] = *(const s16x8*)&As[row * 64 +
                    (((kf * 64 + lg * 16) ^ ((l15 & 7) << 4)) >> 1)];
        }
#pragma unroll
        for (int n = 0; n < NN; ++n) {
            const int row = wc + n * 16 + l15;
#pragma unroll
            for (int kf = 0; kf < 2; ++kf)
                bfr[n][kf] = *(const s16x8*)&Bs[row * 64 +
                    (((kf * 64 + lg * 16) ^ ((l15 & 7) << 4)) >> 1)];
        }
        __builtin_amdgcn_s_setprio(1);
#pragma unroll
        for (int m = 0; m < NM; ++m)
#pragma unroll
            for (int n = 0; n < NN; ++n) {
                acc[m][n] = MFMA16(af[m][0], bfr[n][0], acc[m][n]);
                acc[m][n] = MFMA16(af[m][1], bfr[n][1], acc[m][n]);
            }
        __builtin_amdgcn_s_setprio(0);
    }

    // ---- epilogue
    if (EPI == 0) {
        u16* Y = (u16*)Yv;
        const int whichq = (col0 + wc) >> 10;          // wave-uniform
        if (whichq < 2) {
            // fused RoPE: pairs (n, n+2); out d = j and j+32
            const float sclw = (whichq == 0) ? CEXP : 1.0f;
#pragma unroll
            for (int n = 0; n < 2; ++n) {
                const int cc0 = col0 + wc + n * 16 + l15;
                const int j = n * 16 + l15;            // 0..31
                const float bv0 = bias[cc0];
                const float bv1 = bias[cc0 + 32];
                const int hh = (cc0 >> 6) & (H_ - 1);
#pragma unroll
                for (int m = 0; m < NM; ++m)
#pragma unroll
                    for (int r = 0; r < 4; ++r) {
                        const int rr = row0 + wr + m * 16 + lg * 4 + r;
                        const int b = rr >> 11, s = rr & (S_ - 1);
                        const float2 csv = cs[(s << 5) + j];
                        const float v0 = acc[m][n][r] + bv0;
                        const float v1 = acc[m][n + 2][r] + bv1;
                        const size_t base = (size_t)whichq * BHSD
                            + (((size_t)b * H_ + hh) * S_ + s) * HD_;
                        Y[base + j]      = f2bf((v0 * csv.x - v1 * csv.y) * sclw);
                        Y[base + j + 32] = f2bf((v0 * csv.y + v1 * csv.x) * sclw);
                    }
            }
        } else {
#pragma unroll
            for (int n = 0; n < NN; ++n) {
                const int cc = col0 + wc + n * 16 + l15;
                const float bv = bias[cc];
                const int hh = (cc >> 6) & (H_ - 1), d = cc & 63;
#pragma unroll
                for (int m = 0; m < NM; ++m)
#pragma unroll
                    for (int r = 0; r < 4; ++r) {
                        const int rr = row0 + wr + m * 16 + lg * 4 + r;
                        const int b = rr >> 11, s = rr & (S_ - 1);
                        // V^T with kv perm pi: bits {2,3}->{3,4}, {4}->{5}, {5}->{2}
                        const int sp = (s & ~60) | ((s & 12) << 1)
                                     | ((s & 16) << 1) | ((s & 32) >> 3);
                        Y[2 * BHSD + ((size_t)(b * H_ + hh) * HD_ + d) * S_ + sp] =
                            f2bf(acc[m][n][r] + bv);
                    }
            }
        }
    } else {
#pragma unroll
        for (int n = 0; n < NN; ++n) {
            const int cc = col0 + wc + n * 16 + l15;
            const float bv = bias[cc];
#pragma unroll
            for (int m = 0; m < NM; ++m)
#pragma unroll
                for (int r = 0; r < 4; ++r) {
                    const int rr = row0 + wr + m * 16 + lg * 4 + r;
                    ((float*)Yv)[(size_t)rr * DIM_ + cc] = acc[m][n][r] + bv;
                }
        }
    }
}

// ---------------------------------------------------------------------------
// Causal flash attention, max-free, 128 q-rows per block (8 waves x 16 rows,
// 512 threads). Each K/V staging step serves 8 waves -> per-wave staging
// issue and barrier count per q-row HALVE vs the 64-row design. Wave w owns
// rows qt*128 + w*16 ..+15; its diagonal 64-tile is 2qt+(w>>2), so waves 0-3
// idle for at most the final step. Grid (32 bh FAST, 16 y) = 512 blocks,
// 2/CU; pair map qt = y<8 ? 15-y : y-8 makes each CU's two blocks' step
// counts sum to exactly 34 (static balance). Row-sum l on the matrix pipe
// (ones B-fragment, same accumulator layout as O -> shuffle-free epilogue).
// KV double-buffered via global_load_lds + XOR swizzle; pi-permuted V^T ->
// lane-local PV A-fragments. Output in place into Q.
// ---------------------------------------------------------------------------
__global__ __launch_bounds__(512, 4) void attn_q(
    u16* __restrict__ Q, const u16* __restrict__ K, const u16* __restrict__ VT)
{
    const int bh = blockIdx.x;
    const int y  = blockIdx.y;                   // 0..15
    const int qt = (y < 8) ? (15 - y) : (y - 8); // 128-row tile; paired balance
    const int nsteps = 2 * qt + 2;

    u16* Qg = Q + (size_t)bh * S_ * HD_;
    const u16* Kg = K + (size_t)bh * S_ * HD_;
    const u16* Vg = VT + (size_t)bh * HD_ * S_;  // pi-permuted [64][2048]

    __shared__ u16 Ks[2][64 * 64];   // 2 x 8 KB
    __shared__ u16 Vs[2][64 * 64];   // 2 x 8 KB

    const int tid = threadIdx.x;
    const int w = tid >> 6, lane = tid & 63;
    const int wsub = w & 3;                      // 16-row strip within 64-tile
    const int tdiag = 2 * qt + (w >> 2);         // wave's diagonal 64-tile
    const int q0 = qt * 128 + w * 16;
    const int l15 = lane & 15, lg = lane >> 4;

    // staging: per wave ONE K-chunk + ONE V-chunk (8 rows x 64 cols each)
    const int srow = w * 8 + (lane >> 3);        // 0..63
    const int soff = (((lane & 7) ^ (srow & 7)) << 3);

    auto stage = [&](int bufi, int j0) {
        gl16(&Ks[bufi][w * 512], Kg + (size_t)(j0 + srow) * HD_ + soff);
        gl16(&Vs[bufi][w * 512], Vg + (size_t)srow * S_ + j0 + soff);
    };

    // Q fragments: rows q0 + l15 (rope'd, q pre-scaled by log2(e)/8)
    s16x8 qf[2];
    {
        const u16* qrow = Qg + (size_t)(q0 + l15) * HD_ + lg * 8;
        qf[0] = *(const s16x8*)(qrow);
        qf[1] = *(const s16x8*)(qrow + 32);
    }

    // ones B-fragment (bf16 1.0 in every slot) for MFMA row-sums
    s16x8 onesv;
#pragma unroll
    for (int i = 0; i < 8; ++i) onesv[i] = (short)0x3F80;

    f32x4 o[4], ol;
#pragma unroll
    for (int n = 0; n < 4; ++n) o[n] = (f32x4){0.f, 0.f, 0.f, 0.f};
    ol = (f32x4){0.f, 0.f, 0.f, 0.f};

    stage(0, 0);
    __syncthreads();

    int buf = 0;
    for (int t = 0; t < nsteps; ++t) {
        if (t + 1 < nsteps) stage(buf ^ 1, (t + 1) * 64);   // prefetch

        if (t <= tdiag) {                        // wave-uniform causal gate
            const u16* Kb = Ks[buf];
            const u16* Vb = Vs[buf];

            // ---- swapped QK^T: sc[sub][r] = S[kv=t*64+sub*16+lg*4+r][q0+l15]
            f32x4 sc[4];
            __builtin_amdgcn_s_setprio(1);
#pragma unroll
            for (int sub = 0; sub < 4; ++sub) {
                const int kr = sub * 16 + l15;
                const s16x8 kf0 = *(const s16x8*)&Kb[kr * 64 + ((lg ^ (kr & 7)) << 3)];
                const s16x8 kf1 = *(const s16x8*)&Kb[kr * 64 + (((lg + 4) ^ (kr & 7)) << 3)];
                f32x4 z = (f32x4){0.f, 0.f, 0.f, 0.f};
                z = MFMA16(kf0, qf[0], z);
                sc[sub] = MFMA16(kf1, qf[1], z);
            }
            __builtin_amdgcn_s_setprio(0);

            if (t == tdiag) {   // diagonal 64-tile: aligned 16x16 subs
#pragma unroll
                for (int sub = 0; sub < 4; ++sub) {
                    if (sub == wsub) {
#pragma unroll
                        for (int r = 0; r < 4; ++r)
                            if (lg * 4 + r > l15) sc[sub][r] = -1e30f;
                    } else if (sub > wsub) {
#pragma unroll
                        for (int r = 0; r < 4; ++r) sc[sub][r] = -1e30f;
                    }
                }
            }

            // ---- max-free softmax: p = exp2(s); masked -1e30 -> exp2 -> 0
            float p[4][4];
#pragma unroll
            for (int sub = 0; sub < 4; ++sub)
#pragma unroll
                for (int r = 0; r < 4; ++r)
                    p[sub][r] = __builtin_amdgcn_exp2f(sc[sub][r]);

            // ---- PV + row-sum: lane-local A-fragments (pi-permuted V^T)
            union { s16x8 v; u32 w4[4]; } af[2];
#pragma unroll
            for (int step = 0; step < 2; ++step)
#pragma unroll
                for (int jj = 0; jj < 4; ++jj) {
                    const int sub = (jj >> 1) * 2 + step;
                    const int r0  = (jj & 1) * 2;
                    af[step].w4[jj] = cvt_pk_bf16(p[sub][r0], p[sub][r0 + 1]);
                }
            __builtin_amdgcn_s_setprio(1);
#pragma unroll
            for (int n = 0; n < 4; ++n) {
                const int d = n * 16 + l15;
                const s16x8 vf0 = *(const s16x8*)&Vb[d * 64 + ((lg ^ (d & 7)) << 3)];
                const s16x8 vf1 = *(const s16x8*)&Vb[d * 64 + (((lg + 4) ^ (d & 7)) << 3)];
                o[n] = MFMA16(af[0].v, vf0, o[n]);
                o[n] = MFMA16(af[1].v, vf1, o[n]);
            }
            ol = MFMA16(af[0].v, onesv, ol);    // l[q] = sum_kv p (matrix pipe)
            ol = MFMA16(af[1].v, onesv, ol);
            __builtin_amdgcn_s_setprio(0);
        }

        __syncthreads();   // drains prefetch; buffer handoff
        buf ^= 1;
    }

    // ---- epilogue: O / l (register-local, no shuffles), in place into Q
    f32x4 il;
#pragma unroll
    for (int r = 0; r < 4; ++r) il[r] = 1.f / ol[r];
    u16* orow = Qg + (size_t)(q0 + lg * 4) * HD_ + l15;
#pragma unroll
    for (int r = 0; r < 4; ++r)
#pragma unroll
        for (int n = 0; n < 4; ++n)
            orow[r * HD_ + n * 16] = f2bf(o[n][r] * il[r]);
}

// ---------------------------------------------------------------------------
extern "C" void kernel_launch(void* const* d_in, const int* in_sizes, int n_in,
                              void* d_out, int out_size, void* d_ws, size_t ws_size,
                              hipStream_t stream)
{
    (void)in_sizes; (void)n_in; (void)out_size; (void)ws_size;
    const float* x     = (const float*)d_in[0];
    const float* theta = (const float*)d_in[2];
    const float* Wq    = (const float*)d_in[3];
    const float* bq    = (const float*)d_in[4];
    const float* Wk    = (const float*)d_in[5];
    const float* bk    = (const float*)d_in[6];
    const float* Wv    = (const float*)d_in[7];
    const float* bv    = (const float*)d_in[8];
    const float* Wo    = (const float*)d_in[9];
    const float* bo    = (const float*)d_in[10];
    float* out = (float*)d_out;

    // ws (u16): xb 4M | wtq|wtk|wtv 3M | wto 1M | q 4M | k 4M | VT 4M |
    //           bias3 (3072 f32, padded to 4096) | cs table (2048x32 float2)
    u16* xb  = (u16*)d_ws;
    u16* wtq = xb + (size_t)BS_ * DIM_;
    u16* wtk = wtq + (size_t)DIM_ * DIM_;
    u16* wtv = wtk + (size_t)DIM_ * DIM_;
    u16* wto = wtv + (size_t)DIM_ * DIM_;
    u16* qws = wto + (size_t)DIM_ * DIM_;
    u16* kws = qws + BHSD;
    u16* vtw = kws + BHSD;
    float* bias3 = (float*)(vtw + BHSD);
    float2* cs = (float2*)(bias3 + 4096);

    // fused prep: cvt_x | wtrans(+perm) | cos/sin table | bias concat(+perm)
    prep<<<dim3(6412), dim3(256), 0, stream>>>(
        x, xb, Wq, Wk, Wv, Wo, wtq, wtk, wtv, wto, bq, bk, bv, bias3, theta, cs);

    // fused QKV projection: q,k rope'd head-major; V transposed+pi-permuted
    gemm_mfma<128, 0, 0><<<dim3(32, 24), dim3(256), 0, stream>>>(
        xb, wtq, bias3, qws, cs);

    // max-free attention: 128-row blocks, 8 waves, paired static balance
    attn_q<<<dim3(32, 16), dim3(512), 0, stream>>>(qws, kws, vtw);

    // output projection (head-major A in, fp32 row-major out)
    gemm_mfma<64, 1, 1><<<dim3(32, 16), dim3(256), 0, stream>>>(
        qws, wto, bo, out, cs);
}

// Round 17
// 90.687 us; speedup vs baseline: 1.1842x; 1.0604x over previous
//
#include <hip/hip_runtime.h>
#include <math.h>

#define B_   2
#define S_   2048
#define DIM_ 1024
#define H_   16
#define HD_  64
#define BS_  (B_ * S_)              // 4096
#define BHSD ((size_t)B_ * H_ * S_ * HD_)   // 4M elements
#define CEXP 0.1803368801111244f    // log2(e) / sqrt(64)

typedef unsigned short u16;
typedef unsigned int   u32;
typedef short s16x8 __attribute__((ext_vector_type(8)));
typedef float f32x4 __attribute__((ext_vector_type(4)));

#define MFMA16(a, b, c) __builtin_amdgcn_mfma_f32_16x16x32_bf16((a), (b), (c), 0, 0, 0)

__device__ __forceinline__ u16 f2bf(float f) {
    u32 u = __float_as_uint(f);
    u += 0x7fffu + ((u >> 16) & 1u);            // RNE
    return (u16)(u >> 16);
}
__device__ __forceinline__ u32 cvt_pk_bf16(float a, float b) {
    u32 r;
    asm("v_cvt_pk_bf16_f32 %0, %1, %2" : "=v"(r) : "v"(a), "v"(b));
    return r;
}
// async global->LDS, 16B/lane; LDS dest must be WAVE-UNIFORM base (+lane*16)
__device__ __forceinline__ void gl16(void* lds, const void* g) {
    __builtin_amdgcn_global_load_lds(
        (__attribute__((address_space(1))) void*)(g),
        (__attribute__((address_space(3))) void*)(lds), 16, 0, 0);
}

// ---------------------------------------------------------------------------
// prep: fused cvt_x | weight transpose (+q/k col-permutation) | cos/sin table
// | bias concat (permuted). Dispatch by blockIdx.x range.
// ---------------------------------------------------------------------------
__global__ __launch_bounds__(256) void prep(
    const float* __restrict__ x, u16* __restrict__ xb,
    const float* __restrict__ W0, const float* __restrict__ W1,
    const float* __restrict__ W2, const float* __restrict__ W3,
    u16* __restrict__ T0, u16* __restrict__ T1,
    u16* __restrict__ T2, u16* __restrict__ T3,
    const float* __restrict__ bq, const float* __restrict__ bk,
    const float* __restrict__ bv, float* __restrict__ bias3,
    const float* __restrict__ theta, float2* __restrict__ cs)
{
    __shared__ float tile[32][33];
    const int bid = blockIdx.x, tid = threadIdx.x;

    if (bid < 2048) {                       // ---- x -> bf16
        const int i = bid * 256 + tid;
        const float4 a = *(const float4*)(x + (size_t)i * 8);
        const float4 b = *(const float4*)(x + (size_t)i * 8 + 4);
        s16x8 o;
        o[0] = (short)f2bf(a.x); o[1] = (short)f2bf(a.y);
        o[2] = (short)f2bf(a.z); o[3] = (short)f2bf(a.w);
        o[4] = (short)f2bf(b.x); o[5] = (short)f2bf(b.y);
        o[6] = (short)f2bf(b.z); o[7] = (short)f2bf(b.w);
        *(s16x8*)(xb + (size_t)i * 8) = o;
    } else if (bid < 6144) {                // ---- W transpose
        const int idx = bid - 2048;
        const int z = idx >> 10;
        const float* W; u16* T;
        switch (z) {
            case 0: W = W0; T = T0; break;
            case 1: W = W1; T = T1; break;
            case 2: W = W2; T = T2; break;
            default: W = W3; T = T3; break;
        }
        const int n0 = ((idx >> 5) & 31) * 32, k0 = (idx & 31) * 32;
        const int c = tid & 31, rr = tid >> 5;
#pragma unroll
        for (int i = 0; i < 4; ++i) {
            const int k = rr + i * 8;
            tile[k][c] = W[(size_t)(k0 + k) * DIM_ + n0 + c];
        }
        __syncthreads();
#pragma unroll
        for (int i = 0; i < 4; ++i) {
            const int col = n0 + rr + i * 8;
            int pcol = col;
            if (z < 2) {                    // rope col-perm: even->lo, odd->hi
                const int dd = col & 63;
                const int pd = (dd & 1) ? 32 + (dd >> 1) : (dd >> 1);
                pcol = (col & ~63) | pd;
            }
            T[(size_t)pcol * DIM_ + k0 + c] = f2bf(tile[c][rr + i * 8]);
        }
    } else if (bid < 6400) {                // ---- cos/sin table
        const int idx = bid - 6144;
        const int s = idx * 8 + (tid >> 5), j = tid & 31;
        float sn, cn;
        sincosf((float)s * theta[j], &sn, &cn);
        cs[(s << 5) + j] = make_float2(cn, sn);
    } else {                                // ---- bias concat (permuted q,k)
        const int i = (bid - 6400) * 256 + tid;   // 0..3071
        const int which = i >> 10, local = i & 1023;
        const float v = (which == 0) ? bq[local]
                      : (which == 1) ? bk[local] : bv[local];
        int dst = i;
        if (which < 2) {
            const int dd = local & 63;
            const int pd = (dd & 1) ? 32 + (dd >> 1) : (dd >> 1);
            dst = which * 1024 + (local & ~63) + pd;
        }
        bias3[dst] = v;
    }
}

// ---------------------------------------------------------------------------
// bf16 MFMA GEMM, tile 128 x BN, BK=64, 256 threads (4 waves, 2x2 quadrants).
// A,Bt staged via global_load_lds (16B) into linear LDS, XOR-swizzled via
// pre-swizzled global source.
// EPI 0: bf16 head-major out into q|k|VT.
//   q,k: fused RoPE (weights col-permuted; pairs (n, n+2) in-register) +
//        q pre-scaled by log2(e)/8.
//   VT : V transposed with kv-bit perm pi: bits[5,4,3,2]->[2,5,4,3]
//        (makes the attention PV A-fragment lane-local).
// EPI 1: fp32 row-major out.
// ---------------------------------------------------------------------------
template<int BN, int HMIN, int EPI>
__global__ __launch_bounds__(256, 3) void gemm_mfma(
    const u16* __restrict__ A, const u16* __restrict__ Bt,
    const float* __restrict__ bias, void* __restrict__ Yv,
    const float2* __restrict__ cs)
{
    __shared__ u16 As[128 * 64];
    __shared__ u16 Bs[BN * 64];

    const int tid = threadIdx.x, lane = tid & 63, wid = tid >> 6;
    const int l15 = lane & 15, lg = lane >> 4;
    const int row0 = blockIdx.x * 128, col0 = blockIdx.y * BN;
    const int wr = (wid >> 1) * 64;
    const int wc = (wid & 1) * (BN / 2);
    constexpr int NM = 4, NN = BN / 32, BCH = BN / 32;

    const int l8 = lane >> 3, l7 = lane & 7;
    const int colE = ((l7 ^ l8) << 3);          // k-element offset (swizzled)

    const u16* aptr[4]; u16* aldp[4];
#pragma unroll
    for (int i = 0; i < 4; ++i) {
        const int ci = wid * 4 + i;
        const int rr = row0 + ci * 8 + l8;
        size_t a0;
        if (HMIN)
            a0 = (((size_t)(rr >> 11) * H_) * S_ + (rr & (S_ - 1))) * HD_ + colE;
        else
            a0 = (size_t)rr * DIM_ + colE;
        aptr[i] = A + a0;
        aldp[i] = As + ci * 512;
    }
    const u16* bptr[BCH]; u16* bldp[BCH];
#pragma unroll
    for (int i = 0; i < BCH; ++i) {
        const int ci = wid * BCH + i;
        const int rr = col0 + ci * 8 + l8;
        bptr[i] = Bt + (size_t)rr * DIM_ + colE;
        bldp[i] = Bs + ci * 512;
    }
    const size_t astep = HMIN ? (size_t)S_ * HD_ : 64;

    f32x4 acc[NM][NN];
#pragma unroll
    for (int m = 0; m < NM; ++m)
#pragma unroll
        for (int n = 0; n < NN; ++n) acc[m][n] = (f32x4){0.f, 0.f, 0.f, 0.f};

    for (int k0 = 0; k0 < DIM_; k0 += 64) {
        __syncthreads();   // previous frag reads done
#pragma unroll
        for (int i = 0; i < 4; ++i) gl16(aldp[i], aptr[i]);
#pragma unroll
        for (int i = 0; i < BCH; ++i) gl16(bldp[i], bptr[i]);
#pragma unroll
        for (int i = 0; i < 4; ++i) aptr[i] += astep;
#pragma unroll
        for (int i = 0; i < BCH; ++i) bptr[i] += 64;
        __syncthreads();   // loads drained

        s16x8 af[NM][2], bfr[NN][2];
#pragma unroll
        for (int m = 0; m < NM; ++m) {
            const int row = wr + m * 16 + l15;
#pragma unroll
            for (int kf = 0; kf < 2; ++kf)
                af[m][kf] = *(const s16x8*)&As[row * 64 +
                    (((kf * 64 + lg * 16) ^ ((l15 & 7) << 4)) >> 1)];
        }
#pragma unroll
        for (int n = 0; n < NN; ++n) {
            const int row = wc + n * 16 + l15;
#pragma unroll
            for (int kf = 0; kf < 2; ++kf)
                bfr[n][kf] = *(const s16x8*)&Bs[row * 64 +
                    (((kf * 64 + lg * 16) ^ ((l15 & 7) << 4)) >> 1)];
        }
        __builtin_amdgcn_s_setprio(1);
#pragma unroll
        for (int m = 0; m < NM; ++m)
#pragma unroll
            for (int n = 0; n < NN; ++n) {
                acc[m][n] = MFMA16(af[m][0], bfr[n][0], acc[m][n]);
                acc[m][n] = MFMA16(af[m][1], bfr[n][1], acc[m][n]);
            }
        __builtin_amdgcn_s_setprio(0);
    }

    // ---- epilogue
    if (EPI == 0) {
        u16* Y = (u16*)Yv;
        const int whichq = (col0 + wc) >> 10;          // wave-uniform
        if (whichq < 2) {
            // fused RoPE: pairs (n, n+2); out d = j and j+32
            const float sclw = (whichq == 0) ? CEXP : 1.0f;
#pragma unroll
            for (int n = 0; n < 2; ++n) {
                const int cc0 = col0 + wc + n * 16 + l15;
                const int j = n * 16 + l15;            // 0..31
                const float bv0 = bias[cc0];
                const float bv1 = bias[cc0 + 32];
                const int hh = (cc0 >> 6) & (H_ - 1);
#pragma unroll
                for (int m = 0; m < NM; ++m)
#pragma unroll
                    for (int r = 0; r < 4; ++r) {
                        const int rr = row0 + wr + m * 16 + lg * 4 + r;
                        const int b = rr >> 11, s = rr & (S_ - 1);
                        const float2 csv = cs[(s << 5) + j];
                        const float v0 = acc[m][n][r] + bv0;
                        const float v1 = acc[m][n + 2][r] + bv1;
                        const size_t base = (size_t)whichq * BHSD
                            + (((size_t)b * H_ + hh) * S_ + s) * HD_;
                        Y[base + j]      = f2bf((v0 * csv.x - v1 * csv.y) * sclw);
                        Y[base + j + 32] = f2bf((v0 * csv.y + v1 * csv.x) * sclw);
                    }
            }
        } else {
#pragma unroll
            for (int n = 0; n < NN; ++n) {
                const int cc = col0 + wc + n * 16 + l15;
                const float bv = bias[cc];
                const int hh = (cc >> 6) & (H_ - 1), d = cc & 63;
#pragma unroll
                for (int m = 0; m < NM; ++m)
#pragma unroll
                    for (int r = 0; r < 4; ++r) {
                        const int rr = row0 + wr + m * 16 + lg * 4 + r;
                        const int b = rr >> 11, s = rr & (S_ - 1);
                        // V^T with kv perm pi: bits {2,3}->{3,4}, {4}->{5}, {5}->{2}
                        const int sp = (s & ~60) | ((s & 12) << 1)
                                     | ((s & 16) << 1) | ((s & 32) >> 3);
                        Y[2 * BHSD + ((size_t)(b * H_ + hh) * HD_ + d) * S_ + sp] =
                            f2bf(acc[m][n][r] + bv);
                    }
            }
        }
    } else {
#pragma unroll
        for (int n = 0; n < NN; ++n) {
            const int cc = col0 + wc + n * 16 + l15;
            const float bv = bias[cc];
#pragma unroll
            for (int m = 0; m < NM; ++m)
#pragma unroll
                for (int r = 0; r < 4; ++r) {
                    const int rr = row0 + wr + m * 16 + lg * 4 + r;
                    ((float*)Yv)[(size_t)rr * DIM_ + cc] = acc[m][n][r] + bv;
                }
        }
    }
}

// ---------------------------------------------------------------------------
// Causal flash attention, max-free, COUNTED-VMCNT pipeline (T4).
// One 64-row q-tile per 256-thread block (4 waves x 16 q-rows, all active).
// Grid (32 bh FAST, 32 y band-balanced) = 1024 co-resident blocks (4/CU).
// Per step: stage(t+1) [4 gl16/thread], s_waitcnt vmcnt(4) (t's loads done;
// t+1's stay IN FLIGHT across the barrier), raw s_barrier, compute, raw
// s_barrier (buffer release). No vmcnt(0) drain in the loop. Row-sum l on
// the matrix pipe (ones B-fragment). pi-permuted V^T -> lane-local PV
// A-fragments. Output in place into Q.
// ---------------------------------------------------------------------------
__global__ __launch_bounds__(256, 4) void attn_q(
    u16* __restrict__ Q, const u16* __restrict__ K, const u16* __restrict__ VT)
{
    const int bh = blockIdx.x;
    const int y  = blockIdx.y;                // 0..31
    const int a = y >> 3, r_ = y & 7;
    const int qt = (a == 0) ? (31 - r_) : (a == 1) ? (16 + r_)
                 : (a == 2) ? (15 - r_) : r_;   // band-balanced bijection
    const int nsteps = qt + 1;

    u16* Qg = Q + (size_t)bh * S_ * HD_;
    const u16* Kg = K + (size_t)bh * S_ * HD_;
    const u16* Vg = VT + (size_t)bh * HD_ * S_;   // pi-permuted [64][2048]

    __shared__ u16 Ks[2][64 * 64];   // 2 x 8 KB
    __shared__ u16 Vs[2][64 * 64];   // 2 x 8 KB

    const int tid = threadIdx.x;
    const int w = tid >> 6, lane = tid & 63;
    const int q0 = qt * 64 + w * 16;
    const int l15 = lane & 15, lg = lane >> 4;

    // staging: per wave 2 K-chunks + 2 V-chunks (8 rows x 64 cols each)
    // = 4 gl16 per thread per stage call (vmcnt accounting depends on this)
    const int crow = lane >> 3, cslt = lane & 7;

    auto stage = [&](int bufi, int j0) {
#pragma unroll
        for (int i = 0; i < 2; ++i) {
            const int c = w * 2 + i;                  // chunk 0..7
            const int row = c * 8 + crow;             // 0..63
            const int soff = ((cslt ^ (row & 7)) << 3);
            gl16(&Ks[bufi][c * 512], Kg + (size_t)(j0 + row) * HD_ + soff);
            gl16(&Vs[bufi][c * 512], Vg + (size_t)row * S_ + j0 + soff);
        }
    };

    // Q fragments: rows q0 + l15 (rope'd, q pre-scaled by log2(e)/8)
    s16x8 qf[2];
    {
        const u16* qrow = Qg + (size_t)(q0 + l15) * HD_ + lg * 8;
        qf[0] = *(const s16x8*)(qrow);
        qf[1] = *(const s16x8*)(qrow + 32);
    }

    // ones B-fragment (bf16 1.0 in every slot) for MFMA row-sums
    s16x8 onesv;
#pragma unroll
    for (int i = 0; i < 8; ++i) onesv[i] = (short)0x3F80;

    f32x4 o[4], ol;
#pragma unroll
    for (int n = 0; n < 4; ++n) o[n] = (f32x4){0.f, 0.f, 0.f, 0.f};
    ol = (f32x4){0.f, 0.f, 0.f, 0.f};

    stage(0, 0);   // prologue: tile 0 (4 gl16 outstanding)

    int buf = 0;
    for (int t = 0; t < nsteps; ++t) {
        // issue t+1's loads FIRST, then wait only for t's (counted vmcnt):
        if (t + 1 < nsteps) {
            stage(buf ^ 1, (t + 1) * 64);
            asm volatile("s_waitcnt vmcnt(4)" ::: "memory");
        } else {
            asm volatile("s_waitcnt vmcnt(0)" ::: "memory");
        }
        __builtin_amdgcn_s_barrier();       // all waves' t-loads complete
        __builtin_amdgcn_sched_barrier(0);  // no LDS reads hoisted above

        const u16* Kb = Ks[buf];
        const u16* Vb = Vs[buf];

        // ---- swapped QK^T: sc[sub][r] = S[kv=t*64+sub*16+lg*4+r][q0+l15]
        f32x4 sc[4];
        __builtin_amdgcn_s_setprio(1);
#pragma unroll
        for (int sub = 0; sub < 4; ++sub) {
            const int kr = sub * 16 + l15;
            const s16x8 kf0 = *(const s16x8*)&Kb[kr * 64 + ((lg ^ (kr & 7)) << 3)];
            const s16x8 kf1 = *(const s16x8*)&Kb[kr * 64 + (((lg + 4) ^ (kr & 7)) << 3)];
            f32x4 z = (f32x4){0.f, 0.f, 0.f, 0.f};
            z = MFMA16(kf0, qf[0], z);
            sc[sub] = MFMA16(kf1, qf[1], z);
        }
        __builtin_amdgcn_s_setprio(0);

        if (t == qt) {      // diagonal 64-tile: aligned 16x16 subs
#pragma unroll
            for (int sub = 0; sub < 4; ++sub) {
                if (sub == w) {
#pragma unroll
                    for (int r = 0; r < 4; ++r)
                        if (lg * 4 + r > l15) sc[sub][r] = -1e30f;
                } else if (sub > w) {
#pragma unroll
                    for (int r = 0; r < 4; ++r) sc[sub][r] = -1e30f;
                }
            }
        }

        // ---- max-free softmax: p = exp2(s); masked -1e30 -> exp2 -> 0
        float p[4][4];
#pragma unroll
        for (int sub = 0; sub < 4; ++sub)
#pragma unroll
            for (int r = 0; r < 4; ++r)
                p[sub][r] = __builtin_amdgcn_exp2f(sc[sub][r]);

        // ---- PV + row-sum: lane-local A-fragments (pi-permuted V^T)
        union { s16x8 v; u32 w4[4]; } af[2];
#pragma unroll
        for (int step = 0; step < 2; ++step)
#pragma unroll
            for (int jj = 0; jj < 4; ++jj) {
                const int sub = (jj >> 1) * 2 + step;
                const int r0  = (jj & 1) * 2;
                af[step].w4[jj] = cvt_pk_bf16(p[sub][r0], p[sub][r0 + 1]);
            }
        __builtin_amdgcn_s_setprio(1);
#pragma unroll
        for (int n = 0; n < 4; ++n) {
            const int d = n * 16 + l15;
            const s16x8 vf0 = *(const s16x8*)&Vb[d * 64 + ((lg ^ (d & 7)) << 3)];
            const s16x8 vf1 = *(const s16x8*)&Vb[d * 64 + (((lg + 4) ^ (d & 7)) << 3)];
            o[n] = MFMA16(af[0].v, vf0, o[n]);
            o[n] = MFMA16(af[1].v, vf1, o[n]);
        }
        ol = MFMA16(af[0].v, onesv, ol);    // l[q] = sum_kv p (matrix pipe)
        ol = MFMA16(af[1].v, onesv, ol);
        __builtin_amdgcn_s_setprio(0);

        // release buf for next-iteration overwrite (ds_reads already complete:
        // they fed MFMAs issued above). Raw barrier - NO vmcnt(0) drain.
        __builtin_amdgcn_sched_barrier(0);
        __builtin_amdgcn_s_barrier();
        buf ^= 1;
    }

    // ---- epilogue: O / l (register-local, no shuffles), in place into Q
    f32x4 il;
#pragma unroll
    for (int r = 0; r < 4; ++r) il[r] = 1.f / ol[r];
    u16* orow = Qg + (size_t)(q0 + lg * 4) * HD_ + l15;
#pragma unroll
    for (int r = 0; r < 4; ++r)
#pragma unroll
        for (int n = 0; n < 4; ++n)
            orow[r * HD_ + n * 16] = f2bf(o[n][r] * il[r]);
}

// ---------------------------------------------------------------------------
extern "C" void kernel_launch(void* const* d_in, const int* in_sizes, int n_in,
                              void* d_out, int out_size, void* d_ws, size_t ws_size,
                              hipStream_t stream)
{
    (void)in_sizes; (void)n_in; (void)out_size; (void)ws_size;
    const float* x     = (const float*)d_in[0];
    const float* theta = (const float*)d_in[2];
    const float* Wq    = (const float*)d_in[3];
    const float* bq    = (const float*)d_in[4];
    const float* Wk    = (const float*)d_in[5];
    const float* bk    = (const float*)d_in[6];
    const float* Wv    = (const float*)d_in[7];
    const float* bv    = (const float*)d_in[8];
    const float* Wo    = (const float*)d_in[9];
    const float* bo    = (const float*)d_in[10];
    float* out = (float*)d_out;

    // ws (u16): xb 4M | wtq|wtk|wtv 3M | wto 1M | q 4M | k 4M | VT 4M |
    //           bias3 (3072 f32, padded to 4096) | cs table (2048x32 float2)
    u16* xb  = (u16*)d_ws;
    u16* wtq = xb + (size_t)BS_ * DIM_;
    u16* wtk = wtq + (size_t)DIM_ * DIM_;
    u16* wtv = wtk + (size_t)DIM_ * DIM_;
    u16* wto = wtv + (size_t)DIM_ * DIM_;
    u16* qws = wto + (size_t)DIM_ * DIM_;
    u16* kws = qws + BHSD;
    u16* vtw = kws + BHSD;
    float* bias3 = (float*)(vtw + BHSD);
    float2* cs = (float2*)(bias3 + 4096);

    // fused prep: cvt_x | wtrans(+perm) | cos/sin table | bias concat(+perm)
    prep<<<dim3(6412), dim3(256), 0, stream>>>(
        x, xb, Wq, Wk, Wv, Wo, wtq, wtk, wtv, wto, bq, bk, bv, bias3, theta, cs);

    // fused QKV projection: q,k rope'd head-major; V transposed+pi-permuted
    gemm_mfma<128, 0, 0><<<dim3(32, 24), dim3(256), 0, stream>>>(
        xb, wtq, bias3, qws, cs);

    // max-free attention with counted-vmcnt pipeline (no in-loop drain)
    attn_q<<<dim3(32, 32), dim3(256), 0, stream>>>(qws, kws, vtw);

    // output projection (head-major A in, fp32 row-major out)
    gemm_mfma<64, 1, 1><<<dim3(32, 16), dim3(256), 0, stream>>>(
        qws, wto, bo, out, cs);
}